// Round 11
// baseline (137.112 us; speedup 1.0000x reference)
//
#include <hip/hip_runtime.h>
#include <hip/hip_bf16.h>
#include <math.h>

#define BB 32
#define SS 4096
#define DHH 512
#define EHH 512
#define AA 256

typedef __attribute__((ext_vector_type(8))) short bf16x8;
typedef __attribute__((ext_vector_type(4))) float f32x4;

__device__ __forceinline__ short f2bf(float f) {
    unsigned u = __float_as_uint(f);
    u += 0x7FFFu + ((u >> 16) & 1u);   // RNE
    return (short)(u >> 16);
}

__device__ __forceinline__ unsigned cvt2bf(float a, float b) {
    __hip_bfloat162 h = __float22bfloat162_rn(float2{a, b});  // v_cvt_pk_bf16_f32
    return *(unsigned*)&h;
}

__device__ __forceinline__ float tanh_fast(float x) {
    float e = __expf(2.0f * x);
    return 1.0f - 2.0f * __builtin_amdgcn_rcpf(e + 1.0f);
}

// K0: pack We (E,A) fp32 -> fragment-major bf16, coalesced reads.
__global__ __launch_bounds__(256) void k_packWe(const float* __restrict__ We,
                                                unsigned short* __restrict__ Wpack) {
    int tid = threadIdx.x;
    int e = blockIdx.x * 4 + (tid >> 6);
    int a4 = (tid & 63) * 4;
    float4 t = *(const float4*)&We[(size_t)e * AA + a4];
    int kk = e >> 5, hi = (e >> 3) & 3, j = e & 7;
    const float* tf = (const float*)&t;
    #pragma unroll
    for (int u = 0; u < 4; ++u) {
        int a = a4 + u;
        int ct = a >> 4, lo = a & 15;
        Wpack[((size_t)((kk * 16 + ct) * 64 + hi * 16 + lo)) * 8 + j] = (unsigned short)f2bf(tf[u]);
    }
}

// K1: dec_proj partials, 8-way K-split
__global__ __launch_bounds__(256) void k_decproj(const float* __restrict__ h,
                                                 const float* __restrict__ Wd,
                                                 float* __restrict__ dp8) {
    int b = blockIdx.x, sp = blockIdx.y;
    int a = threadIdx.x;
    const float* hb = h + (size_t)b * DHH + sp * 64;
    const float* wb = Wd + (size_t)(sp * 64) * AA + a;
    float acc = 0.f;
    #pragma unroll 16
    for (int i = 0; i < 64; ++i)
        acc = fmaf(hb[i], wb[(size_t)i * AA], acc);
    dp8[((size_t)b * 8 + sp) * AA + a] = acc;
}

// K2: persistent multi-chunk pipeline. 512 blocks (32 b x 16 slots), each block
// processes 8 consecutive 32-row chunks with double-buffered LDS (2x32KB).
// Chunk c+1's global loads are issued at the TOP of chunk c's compute and
// written to the other buffer at the END (T14 issue-early/write-late) ->
// every block keeps ~64KB continuously in flight -> HBM duty cycle ~100%.
// Per wave: all 32 rows (rt 0..1) x cols w*32..+32 (ct 0..1).
__global__ __launch_bounds__(512) void k_energy_mfma(const float* __restrict__ enc,
                                                     const unsigned short* __restrict__ Wpack,
                                                     const float* __restrict__ dp8,
                                                     const float* __restrict__ v,
                                                     const int* __restrict__ mask,
                                                     float* __restrict__ energy,
                                                     float* __restrict__ pctx,
                                                     float2* __restrict__ ml) {
    __shared__ unsigned short AbufA[8][32 * 64];   // 32 KB
    __shared__ unsigned short AbufB[8][32 * 64];   // 32 KB
    __shared__ float part[8][32];

    int slot = blockIdx.x;          // 512 = 32 b * 16 slots
    int b  = slot >> 4;
    int c0 = (slot & 15) * 8;       // first of 8 chunks (128 chunks of 32 rows per b)
    int tid = threadIdx.x;
    int l  = tid & 63;
    int w  = tid >> 6;              // 0..7
    int lo = l & 15;
    int hi = l >> 4;

    // staging: thread -> row r (0..31), col group q (0..15) of 32 floats
    int r = tid >> 4;
    int q = tid & 15;
    const float* gb0 = enc + ((size_t)(b * SS + c0 * 32 + r)) * EHH + q * 32;
    int ktw = q >> 1, half = q & 1;
    int wo[4];
    #pragma unroll
    for (int i = 0; i < 4; ++i)
        wo[i] = ktw * 4096 + ((r * 128 + half * 64 + i * 16) ^ ((r & 7) << 4));

    // hoisted epilogue constants (per-thread cols n = w*32 + ct*16 + lo)
    float dpv[2], vv[2];
    #pragma unroll
    for (int ct = 0; ct < 2; ++ct) {
        int n = w * 32 + ct * 16 + lo;
        float d = 0.f;
        #pragma unroll
        for (int sp = 0; sp < 8; ++sp)
            d += dp8[((size_t)b * 8 + sp) * AA + n];
        dpv[ct] = d;
        vv[ct]  = v[n];
    }

    const unsigned short* bbase = Wpack + ((size_t)(w * 2) * 64 + l) * 8;

    // ---- prologue: stage chunk 0 into AbufA ----
    float4 st[8];
    #pragma unroll
    for (int i = 0; i < 8; ++i) st[i] = *(const float4*)(gb0 + i * 4);
    unsigned short* bufc = &AbufA[0][0];
    unsigned short* bufn = &AbufB[0][0];
    #pragma unroll
    for (int i = 0; i < 4; ++i) {
        uint4 wv = { cvt2bf(st[2*i].x, st[2*i].y),   cvt2bf(st[2*i].z, st[2*i].w),
                     cvt2bf(st[2*i+1].x, st[2*i+1].y), cvt2bf(st[2*i+1].z, st[2*i+1].w) };
        *(uint4*)((char*)bufc + wo[i]) = wv;
    }
    __syncthreads();

    for (int c = 0; c < 8; ++c) {
        int cg = c0 + c;            // global chunk id (0..127)
        int s0 = cg * 32;

        // issue chunk c+1 loads NOW (in flight during all of chunk c's compute)
        if (c < 7) {
            const float* gb = gb0 + (size_t)(c + 1) * 32 * EHH;
            #pragma unroll
            for (int i = 0; i < 8; ++i) st[i] = *(const float4*)(gb + i * 4);
        }

        // ---- MFMA loop on bufc, B 2-deep prefetch from L2 ----
        f32x4 acc[2][2];
        #pragma unroll
        for (int rt = 0; rt < 2; ++rt)
            #pragma unroll
            for (int ct = 0; ct < 2; ++ct)
                acc[rt][ct] = (f32x4){0.f, 0.f, 0.f, 0.f};

        bf16x8 bn0[2], bn1[2];
        #pragma unroll
        for (int ct = 0; ct < 2; ++ct) bn0[ct] = *(const bf16x8*)(bbase + ct * 512);
        #pragma unroll
        for (int ct = 0; ct < 2; ++ct) bn1[ct] = *(const bf16x8*)(bbase + 8192 + ct * 512);

        #pragma unroll
        for (int g = 0; g < 16; ++g) {
            int kt = g >> 1, ks = g & 1;
            bf16x8 bcur[2];
            #pragma unroll
            for (int ct = 0; ct < 2; ++ct) { bcur[ct] = bn0[ct]; bn0[ct] = bn1[ct]; }
            if (g + 2 < 16) {
                const unsigned short* bp = bbase + (size_t)(g + 2) * 8192;
                #pragma unroll
                for (int ct = 0; ct < 2; ++ct)
                    bn1[ct] = *(const bf16x8*)(bp + ct * 512);
            }
            bf16x8 afr[2];
            #pragma unroll
            for (int rt = 0; rt < 2; ++rt) {
                int row = rt * 16 + lo;
                afr[rt] = *(const bf16x8*)((char*)bufc + kt * 4096
                           + ((row * 128 + ks * 64 + hi * 16) ^ ((row & 7) << 4)));
            }
            #pragma unroll
            for (int rt = 0; rt < 2; ++rt)
                #pragma unroll
                for (int ct = 0; ct < 2; ++ct)
                    acc[rt][ct] = __builtin_amdgcn_mfma_f32_16x16x32_bf16(afr[rt], bcur[ct], acc[rt][ct], 0, 0, 0);
        }

        // ---- energy reduce: ps = partial row-sums over this wave's 32 cols ----
        float ps[2][4];
        #pragma unroll
        for (int rt = 0; rt < 2; ++rt)
            #pragma unroll
            for (int rr = 0; rr < 4; ++rr) ps[rt][rr] = 0.f;
        #pragma unroll
        for (int ct = 0; ct < 2; ++ct)
            #pragma unroll
            for (int rt = 0; rt < 2; ++rt)
                #pragma unroll
                for (int rr = 0; rr < 4; ++rr)
                    ps[rt][rr] += vv[ct] * tanh_fast(acc[rt][ct][rr] + dpv[ct]);
        #pragma unroll
        for (int off = 1; off < 16; off <<= 1)
            #pragma unroll
            for (int rt = 0; rt < 2; ++rt)
                #pragma unroll
                for (int rr = 0; rr < 4; ++rr)
                    ps[rt][rr] += __shfl_xor(ps[rt][rr], off);
        if (lo == 0) {
            #pragma unroll
            for (int rt = 0; rt < 2; ++rt)
                #pragma unroll
                for (int rr = 0; rr < 4; ++rr)
                    part[w][rt * 16 + 4 * hi + rr] = ps[rt][rr];
        }
        __syncthreads();

        // ---- stats: computed redundantly in every wave (no extra barrier) ----
        float e = 0.f;
        #pragma unroll
        for (int i = 0; i < 8; ++i) e += part[i][l & 31];
        if (w == 0 && l < 32) energy[(size_t)b * SS + s0 + l] = e;
        int mk = mask[(size_t)b * SS + s0 + (l & 31)];
        float val = mk ? e : -INFINITY;
        float m = val;
        #pragma unroll
        for (int off = 1; off < 32; off <<= 1) m = fmaxf(m, __shfl_xor(m, off));
        float wgt = (val == -INFINITY) ? 0.f : __expf(val - m);
        float lsum = wgt;
        #pragma unroll
        for (int off = 1; off < 32; off <<= 1) lsum += __shfl_xor(lsum, off);
        if (w == 0 && l == 0) ml[(size_t)b * 128 + cg] = float2{m, lsum};

        // ---- partial context: thread owns col tid; wgt[s] via __shfl ----
        {
            int ktp = tid >> 6;
            int c2  = (tid & 63) * 2;
            float a0 = 0.f;
            #pragma unroll 8
            for (int s = 0; s < 32; ++s) {
                float wv_ = __shfl(wgt, s);
                unsigned short u = *(const unsigned short*)((char*)bufc + ktp * 4096
                                    + ((s * 128 + c2) ^ ((s & 7) << 4)));
                a0 = fmaf(wv_, __uint_as_float(((unsigned)u) << 16), a0);
            }
            pctx[((size_t)(b * 128 + cg)) * 512 + tid] = a0;
        }

        // ---- write chunk c+1 into the other buffer (loads issued ~2K cy ago) ----
        if (c < 7) {
            #pragma unroll
            for (int i = 0; i < 4; ++i) {
                uint4 wv = { cvt2bf(st[2*i].x, st[2*i].y),   cvt2bf(st[2*i].z, st[2*i].w),
                             cvt2bf(st[2*i+1].x, st[2*i+1].y), cvt2bf(st[2*i+1].z, st[2*i+1].w) };
                *(uint4*)((char*)bufn + wo[i]) = wv;
            }
        }
        __syncthreads();
        unsigned short* t = bufc; bufc = bufn; bufn = t;
    }
}

// K3: fused final softmax (attn) + context. Grid (B, 4 slices), 512 thr.
__global__ __launch_bounds__(512) void k_final(const float* __restrict__ energy,
                                               const int* __restrict__ mask,
                                               const float2* __restrict__ ml,
                                               const float* __restrict__ pctx,
                                               float* __restrict__ attn,
                                               float* __restrict__ ctx) {
    __shared__ float wm[8], wz[8];
    __shared__ float red[4][128];
    int b = blockIdx.x, sl = blockIdx.y;
    int tid = threadIdx.x;
    int l = tid & 63, w = tid >> 6;

    float2 p = float2{-INFINITY, 0.f};
    if (tid < 128) p = ml[(size_t)b * 128 + tid];
    float m = p.x;
    #pragma unroll
    for (int off = 1; off < 64; off <<= 1) m = fmaxf(m, __shfl_xor(m, off));
    if (!l) wm[w] = m;
    __syncthreads();
    float M = wm[0];
    #pragma unroll
    for (int i = 1; i < 8; ++i) M = fmaxf(M, wm[i]);
    float z = (p.x == -INFINITY) ? 0.f : __expf(p.x - M) * p.y;
    #pragma unroll
    for (int off = 1; off < 64; off <<= 1) z += __shfl_xor(z, off);
    if (!l) wz[w] = z;
    __syncthreads();
    float Z = 0.f;
    #pragma unroll
    for (int i = 0; i < 8; ++i) Z += wz[i];
    float invZ = (Z > 0.f) ? 1.0f / Z : 0.f;

    #pragma unroll
    for (int it = 0; it < 2; ++it) {
        int s = sl * 1024 + it * 512 + tid;
        float e = energy[(size_t)b * SS + s];
        int mk = mask[(size_t)b * SS + s];
        attn[(size_t)b * SS + s] = mk ? __expf(e - M) * invZ : 0.f;
    }

    {
        int cg = tid >> 7;            // 0..3
        int e  = sl * 128 + (tid & 127);
        float acc = 0.f;
        #pragma unroll 8
        for (int i = 0; i < 32; ++i) {
            int c = cg * 32 + i;
            float2 pc = ml[(size_t)b * 128 + c];
            float sc = (pc.x == -INFINITY) ? 0.f : __expf(pc.x - M);
            acc = fmaf(sc, pctx[((size_t)(b * 128 + c)) * 512 + e], acc);
        }
        red[cg][tid & 127] = acc;
    }
    __syncthreads();
    if (tid < 128) {
        float s = red[0][tid] + red[1][tid] + red[2][tid] + red[3][tid];
        ctx[(size_t)b * EHH + sl * 128 + tid] = s * invZ;
    }
}

extern "C" void kernel_launch(void* const* d_in, const int* in_sizes, int n_in,
                              void* d_out, int out_size, void* d_ws, size_t ws_size,
                              hipStream_t stream) {
    const float* h    = (const float*)d_in[0];
    const float* enc  = (const float*)d_in[1];
    const int*   mask = (const int*)d_in[2];
    const float* Wd   = (const float*)d_in[3];
    const float* We   = (const float*)d_in[4];
    const float* v    = (const float*)d_in[5];

    float* out  = (float*)d_out;
    float* ctx  = out;              // (B, EH)
    float* attn = out + BB * EHH;   // (B, S)

    char* ws = (char*)d_ws;
    float*          dp8    = (float*)ws;                          // 256 KB
    float*          energy = (float*)(ws + (256 << 10));          // 512 KB
    unsigned short* Wpack  = (unsigned short*)(ws + (768 << 10)); // 256 KB
    float*          pctx   = (float*)(ws + (1 << 20));            // 8 MB
    float2*         ml     = (float2*)(ws + (9 << 20));           // 32 KB

    k_packWe<<<128, 256, 0, stream>>>(We, Wpack);
    k_decproj<<<dim3(BB, 8), AA, 0, stream>>>(h, Wd, dp8);
    k_energy_mfma<<<BB * 16, 512, 0, stream>>>(enc, Wpack, dp8, v, mask,
                                               energy, pctx, ml);
    k_final<<<dim3(BB, 4), 512, 0, stream>>>(energy, mask, ml, pctx, attn, ctx);
}

// Round 12
// 94.697 us; speedup vs baseline: 1.4479x; 1.4479x over previous
//
#include <hip/hip_runtime.h>
#include <hip/hip_bf16.h>
#include <math.h>

#define BB 32
#define SS 4096
#define DHH 512
#define EHH 512
#define AA 256

typedef __attribute__((ext_vector_type(8))) short bf16x8;
typedef __attribute__((ext_vector_type(4))) float f32x4;

__device__ __forceinline__ short f2bf(float f) {
    unsigned u = __float_as_uint(f);
    u += 0x7FFFu + ((u >> 16) & 1u);   // RNE
    return (short)(u >> 16);
}

__device__ __forceinline__ unsigned cvt2bf(float a, float b) {
    __hip_bfloat162 h = __float22bfloat162_rn(float2{a, b});  // v_cvt_pk_bf16_f32
    return *(unsigned*)&h;
}

__device__ __forceinline__ float tanh_fast(float x) {
    float e = __expf(2.0f * x);
    return 1.0f - 2.0f * __builtin_amdgcn_rcpf(e + 1.0f);
}

// K0: pack We (E,A) fp32 -> fragment-major bf16, coalesced reads.
__global__ __launch_bounds__(256) void k_packWe(const float* __restrict__ We,
                                                unsigned short* __restrict__ Wpack) {
    int tid = threadIdx.x;
    int e = blockIdx.x * 4 + (tid >> 6);
    int a4 = (tid & 63) * 4;
    float4 t = *(const float4*)&We[(size_t)e * AA + a4];
    int kk = e >> 5, hi = (e >> 3) & 3, j = e & 7;
    const float* tf = (const float*)&t;
    #pragma unroll
    for (int u = 0; u < 4; ++u) {
        int a = a4 + u;
        int ct = a >> 4, lo = a & 15;
        Wpack[((size_t)((kk * 16 + ct) * 64 + hi * 16 + lo)) * 8 + j] = (unsigned short)f2bf(tf[u]);
    }
}

// K1: dec_proj partials, 8-way K-split
__global__ __launch_bounds__(256) void k_decproj(const float* __restrict__ h,
                                                 const float* __restrict__ Wd,
                                                 float* __restrict__ dp8) {
    int b = blockIdx.x, sp = blockIdx.y;
    int a = threadIdx.x;
    const float* hb = h + (size_t)b * DHH + sp * 64;
    const float* wb = Wd + (size_t)(sp * 64) * AA + a;
    float acc = 0.f;
    #pragma unroll 16
    for (int i = 0; i < 64; ++i)
        acc = fmaf(hb[i], wb[(size_t)i * AA], acc);
    dp8[((size_t)b * 8 + sp) * AA + a] = acc;
}

// K2: fused energy GEMM + local softmax stats + partial context.
// R10 structure (64-row chunks, 512 thr, single-barrier staging, B 2-deep
// prefetch). NEW in R12: pctx epilogue via 8x ds_read_b128/lane + shfl reduce
// (was 128 scalar LDS ops/thread); stats all-wave-redundant (drops wbuf+barrier).
__global__ __launch_bounds__(512, 4) void k_energy_mfma(const float* __restrict__ enc,
                                                        const unsigned short* __restrict__ Wpack,
                                                        const float* __restrict__ dp8,
                                                        const float* __restrict__ v,
                                                        const int* __restrict__ mask,
                                                        float* __restrict__ energy,
                                                        float* __restrict__ pctx,
                                                        float2* __restrict__ ml) {
    __shared__ unsigned short Abuf[8][64 * 64];   // 64 KB, swizzled bf16
    __shared__ float part[8][64];                 // 2 KB

    int bk = blockIdx.x;            // 2048 = 32 b * 64 chunks
    int b  = bk >> 6;
    int chunk = bk & 63;
    int s0 = chunk * 64;
    int tid = threadIdx.x;
    int l  = tid & 63;
    int w  = tid >> 6;              // 0..7
    int lo = l & 15;
    int hi = l >> 4;

    // staging: thread -> row r (0..63), 8-float group q (0..7), all 8 regions
    int r = tid >> 3;
    int q = tid & 7;
    const float* gbase = enc + ((size_t)b * SS + s0 + r) * EHH + q * 8;
    int wb0 = ((r * 128 + q * 16) ^ ((r & 7) << 4));

    // ---- phase 1: issue ALL A-loads, cvt+write all 8 regions, 1 barrier ----
    float4 sva[8], svb[8];
    #pragma unroll
    for (int kt = 0; kt < 8; ++kt) {
        const float4* gp = (const float4*)(gbase + kt * 64);
        sva[kt] = gp[0]; svb[kt] = gp[1];
    }
    #pragma unroll
    for (int kt = 0; kt < 8; ++kt) {
        uint4 w0 = { cvt2bf(sva[kt].x, sva[kt].y), cvt2bf(sva[kt].z, sva[kt].w),
                     cvt2bf(svb[kt].x, svb[kt].y), cvt2bf(svb[kt].z, svb[kt].w) };
        *(uint4*)((char*)Abuf[kt] + wb0) = w0;
    }
    __syncthreads();

    // ---- phase 2: barrier-free MFMA loop, B 2-deep prefetch from L2 ----
    f32x4 acc[4][2];
    #pragma unroll
    for (int rt = 0; rt < 4; ++rt)
        #pragma unroll
        for (int ct = 0; ct < 2; ++ct)
            acc[rt][ct] = (f32x4){0.f, 0.f, 0.f, 0.f};

    const unsigned short* bbase = Wpack + ((size_t)(w * 2) * 64 + l) * 8;  // + g*8192 + ct*512
    bf16x8 bn0[2], bn1[2];
    #pragma unroll
    for (int ct = 0; ct < 2; ++ct) bn0[ct] = *(const bf16x8*)(bbase + ct * 512);
    #pragma unroll
    for (int ct = 0; ct < 2; ++ct) bn1[ct] = *(const bf16x8*)(bbase + 8192 + ct * 512);

    #pragma unroll
    for (int g = 0; g < 16; ++g) {          // g = kt*2 + ks
        int kt = g >> 1, ks = g & 1;
        bf16x8 bcur[2];
        #pragma unroll
        for (int ct = 0; ct < 2; ++ct) { bcur[ct] = bn0[ct]; bn0[ct] = bn1[ct]; }
        if (g + 2 < 16) {
            const unsigned short* bp = bbase + (size_t)(g + 2) * 8192;
            #pragma unroll
            for (int ct = 0; ct < 2; ++ct)
                bn1[ct] = *(const bf16x8*)(bp + ct * 512);
        }
        const char* lb = (const char*)Abuf[kt];
        bf16x8 afr[4];
        #pragma unroll
        for (int rt = 0; rt < 4; ++rt) {
            int row = rt * 16 + lo;
            afr[rt] = *(const bf16x8*)(lb + ((row * 128 + ks * 64 + hi * 16) ^ ((row & 7) << 4)));
        }
        #pragma unroll
        for (int rt = 0; rt < 4; ++rt)
            #pragma unroll
            for (int ct = 0; ct < 2; ++ct)
                acc[rt][ct] = __builtin_amdgcn_mfma_f32_16x16x32_bf16(afr[rt], bcur[ct], acc[rt][ct], 0, 0, 0);
    }

    // ---- energy epilogue: ps[rt][rr] = partial row-sum over this wave's 32 cols ----
    float ps[4][4];
    #pragma unroll
    for (int rt = 0; rt < 4; ++rt)
        #pragma unroll
        for (int rr = 0; rr < 4; ++rr) ps[rt][rr] = 0.f;
    #pragma unroll
    for (int ct = 0; ct < 2; ++ct) {
        int n = w * 32 + ct * 16 + lo;
        float dpv = 0.f;
        #pragma unroll
        for (int sp = 0; sp < 8; ++sp)
            dpv += dp8[((size_t)b * 8 + sp) * AA + n];
        float vv = v[n];
        #pragma unroll
        for (int rt = 0; rt < 4; ++rt)
            #pragma unroll
            for (int rr = 0; rr < 4; ++rr)
                ps[rt][rr] += vv * tanh_fast(acc[rt][ct][rr] + dpv);
    }
    #pragma unroll
    for (int off = 1; off < 16; off <<= 1)
        #pragma unroll
        for (int rt = 0; rt < 4; ++rt)
            #pragma unroll
            for (int rr = 0; rr < 4; ++rr)
                ps[rt][rr] += __shfl_xor(ps[rt][rr], off);
    if (lo == 0) {
        #pragma unroll
        for (int rt = 0; rt < 4; ++rt)
            #pragma unroll
            for (int rr = 0; rr < 4; ++rr)
                part[w][rt * 16 + 4 * hi + rr] = ps[rt][rr];
    }
    __syncthreads();

    // ---- stats: all waves redundantly (lane = row); no wbuf, no extra barrier ----
    float e = 0.f;
    #pragma unroll
    for (int i = 0; i < 8; ++i) e += part[i][l];
    if (w == 0) energy[(size_t)b * SS + s0 + l] = e;
    int mk = mask[(size_t)b * SS + s0 + l];
    float val = mk ? e : -INFINITY;
    float m = val;
    #pragma unroll
    for (int off = 1; off < 64; off <<= 1) m = fmaxf(m, __shfl_xor(m, off));
    float wgt = (val == -INFINITY) ? 0.f : __expf(val - m);
    float lsum = wgt;
    #pragma unroll
    for (int off = 1; off < 64; off <<= 1) lsum += __shfl_xor(lsum, off);
    if (w == 0 && l == 0) ml[(size_t)b * 64 + chunk] = float2{m, lsum};

    // ---- partial context: wave w owns LDS region w (enc cols w*64..+64).
    // Lane: col-chunk cc = l&7 (8 bf16 cols), row-group rg = l>>3 (8 rows).
    // 8 ds_read_b128 per lane, fma into 8 col-accs, xor-shfl reduce over rg.
    {
        int cc = l & 7;
        int rg = l >> 3;
        const char* lb = (const char*)Abuf[w];
        float acc8[8];
        #pragma unroll
        for (int jj = 0; jj < 8; ++jj) acc8[jj] = 0.f;
        #pragma unroll
        for (int i = 0; i < 8; ++i) {
            int row = rg * 8 + i;
            float wr = __shfl(wgt, row);
            bf16x8 u = *(const bf16x8*)(lb + row * 128 + ((cc * 16) ^ (i << 4)));
            #pragma unroll
            for (int jj = 0; jj < 8; ++jj)
                acc8[jj] = fmaf(wr, __uint_as_float(((unsigned)(unsigned short)u[jj]) << 16), acc8[jj]);
        }
        #pragma unroll
        for (int off = 8; off < 64; off <<= 1)
            #pragma unroll
            for (int jj = 0; jj < 8; ++jj)
                acc8[jj] += __shfl_xor(acc8[jj], off);
        if (l < 8) {
            float* dst = &pctx[((size_t)(b * 64 + chunk)) * 512 + w * 64 + cc * 8];
            *(float4*)dst = (float4){acc8[0], acc8[1], acc8[2], acc8[3]};
            *(float4*)(dst + 4) = (float4){acc8[4], acc8[5], acc8[6], acc8[7]};
        }
    }
}

// K3: fused final softmax (attn) + context. Grid (B, 4 slices), 512 thr.
__global__ __launch_bounds__(512) void k_final(const float* __restrict__ energy,
                                               const int* __restrict__ mask,
                                               const float2* __restrict__ ml,
                                               const float* __restrict__ pctx,
                                               float* __restrict__ attn,
                                               float* __restrict__ ctx) {
    __shared__ float scal[64];
    __shared__ float sM, sZ;
    __shared__ float red[4][128];
    int b = blockIdx.x, sl = blockIdx.y;
    int tid = threadIdx.x;

    if (tid < 64) {                 // wave 0: chunk stats (64 chunks)
        float2 p = ml[(size_t)b * 64 + tid];
        float m = p.x;
        #pragma unroll
        for (int off = 1; off < 64; off <<= 1) m = fmaxf(m, __shfl_xor(m, off));
        float sc = (p.x == -INFINITY) ? 0.f : __expf(p.x - m);
        scal[tid] = sc;
        float z = sc * p.y;
        #pragma unroll
        for (int off = 1; off < 64; off <<= 1) z += __shfl_xor(z, off);
        if (tid == 0) { sM = m; sZ = z; }
    }
    __syncthreads();
    float M = sM;
    float invZ = (sZ > 0.f) ? 1.0f / sZ : 0.f;

    // attn slice: 2 iters of 512
    #pragma unroll
    for (int it = 0; it < 2; ++it) {
        int s = sl * 1024 + it * 512 + tid;
        float e = energy[(size_t)b * SS + s];
        int mk = mask[(size_t)b * SS + s];
        attn[(size_t)b * SS + s] = mk ? __expf(e - M) * invZ : 0.f;
    }

    // ctx slice: 4 groups of 128 threads, each covers 16 chunks, LDS-reduce
    {
        int cg = tid >> 7;            // 0..3
        int e  = sl * 128 + (tid & 127);
        float acc = 0.f;
        #pragma unroll 8
        for (int i = 0; i < 16; ++i) {
            int c = cg * 16 + i;
            acc = fmaf(scal[c], pctx[((size_t)(b * 64 + c)) * 512 + e], acc);
        }
        red[cg][tid & 127] = acc;
    }
    __syncthreads();
    if (tid < 128) {
        float s = red[0][tid] + red[1][tid] + red[2][tid] + red[3][tid];
        ctx[(size_t)b * EHH + sl * 128 + tid] = s * invZ;
    }
}

extern "C" void kernel_launch(void* const* d_in, const int* in_sizes, int n_in,
                              void* d_out, int out_size, void* d_ws, size_t ws_size,
                              hipStream_t stream) {
    const float* h    = (const float*)d_in[0];
    const float* enc  = (const float*)d_in[1];
    const int*   mask = (const int*)d_in[2];
    const float* Wd   = (const float*)d_in[3];
    const float* We   = (const float*)d_in[4];
    const float* v    = (const float*)d_in[5];

    float* out  = (float*)d_out;
    float* ctx  = out;              // (B, EH)
    float* attn = out + BB * EHH;   // (B, S)

    char* ws = (char*)d_ws;
    float*          dp8    = (float*)ws;                          // 256 KB
    float*          energy = (float*)(ws + (256 << 10));          // 512 KB
    unsigned short* Wpack  = (unsigned short*)(ws + (768 << 10)); // 256 KB
    float*          pctx   = (float*)(ws + (1 << 20));            // 4 MB
    float2*         ml     = (float2*)(ws + (6 << 20));           // 16 KB

    k_packWe<<<128, 256, 0, stream>>>(We, Wpack);
    k_decproj<<<dim3(BB, 8), AA, 0, stream>>>(h, Wd, dp8);
    k_energy_mfma<<<BB * SS / 64, 512, 0, stream>>>(enc, Wpack, dp8, v, mask,
                                                    energy, pctx, ml);
    k_final<<<dim3(BB, 4), 512, 0, stream>>>(energy, mask, ml, pctx, attn, ctx);
}